// Round 1
// baseline (19360.533 us; speedup 1.0000x reference)
//
#include <hip/hip_runtime.h>

#define NGRAPH 2048
#define MAXLEN 254
#define NNODE 520192      // NGRAPH * MAXLEN
#define NEDGE 4161536     // NNODE * 8
#define NF 78
#define BN_EPS 1e-5f
#define LN_EPS 1e-5f

// ---------------- layer-1 first GEMM: t = x @ w1a (N x 78 @ 78 x 64); also zero BN stats
__global__ __launch_bounds__(256) void k_gemm78(const float* __restrict__ x,
                                                const float* __restrict__ W,
                                                float* __restrict__ out,
                                                float* __restrict__ stats) {
    __shared__ float sW[NF * 64];
    for (int i = threadIdx.x; i < NF * 64; i += 256) sW[i] = W[i];
    if (blockIdx.x == 0) {
        for (int i = threadIdx.x; i < 5 * 128; i += 256) stats[i] = 0.f;
    }
    __syncthreads();
    int node = blockIdx.x * 256 + threadIdx.x;  // N divisible by 256
    const float* xr = x + (size_t)node * NF;    // rows are 8B-aligned (312B) -> float2
    float a[64];
#pragma unroll
    for (int c = 0; c < 64; c++) a[c] = 0.f;
    for (int k2 = 0; k2 < NF / 2; k2++) {
        float2 xv = ((const float2*)xr)[k2];
        const float* w0 = sW + (2 * k2) * 64;
#pragma unroll
        for (int c = 0; c < 64; c++) a[c] += xv.x * w0[c];
#pragma unroll
        for (int c = 0; c < 64; c++) a[c] += xv.y * w0[64 + c];
    }
    float* orow = out + ((size_t)node << 6);
#pragma unroll
    for (int c = 0; c < 64; c += 4)
        *(float4*)(orow + c) = make_float4(a[c], a[c + 1], a[c + 2], a[c + 3]);
}

// ---------------- acc = src (N*64 floats as float4)
__global__ __launch_bounds__(256) void k_copy(const float4* __restrict__ src,
                                              float4* __restrict__ dst) {
    size_t i = (size_t)blockIdx.x * 256 + threadIdx.x;
    dst[i] = src[i];
}

// ---------------- edge aggregation: acc[dst] += h[src]; 16 lanes/edge, float4 per lane
__global__ __launch_bounds__(256) void k_edge(const float* __restrict__ h,
                                              const int* __restrict__ ei,
                                              float* __restrict__ acc) {
    size_t t = (size_t)blockIdx.x * 256 + threadIdx.x;  // NEDGE*16 threads exactly
    int e = (int)(t >> 4);
    int g = (int)(t & 15);
    int s = ei[e];
    int d = ei[NEDGE + e];
    const float4 v = *(const float4*)(h + ((size_t)s << 6) + g * 4);
    float* p = acc + ((size_t)d << 6) + g * 4;
    atomicAdd(p, v.x);
    atomicAdd(p + 1, v.y);
    atomicAdd(p + 2, v.z);
    atomicAdd(p + 3, v.w);
}

// ---------------- shared second matmul: out = relu(a @ W2 + b2)
__device__ __forceinline__ void second_matmul(const float (&a)[64], const float* __restrict__ sW2,
                                              const float* __restrict__ sb2,
                                              float* __restrict__ orow) {
#pragma unroll
    for (int cb = 0; cb < 64; cb += 16) {
        float o[16];
#pragma unroll
        for (int j = 0; j < 16; j++) o[j] = sb2[cb + j];
#pragma unroll
        for (int k = 0; k < 64; k++) {
            float ak = a[k];
#pragma unroll
            for (int j = 0; j < 16; j++) o[j] += ak * sW2[k * 64 + cb + j];
        }
#pragma unroll
        for (int j = 0; j < 16; j += 4)
            *(float4*)(orow + cb + j) =
                make_float4(fmaxf(o[j], 0.f), fmaxf(o[j + 1], 0.f),
                            fmaxf(o[j + 2], 0.f), fmaxf(o[j + 3], 0.f));
    }
}

// ---------------- layer-1 tail: h = relu(relu(acc + b1a) @ w1b + b1b)
__global__ __launch_bounds__(256) void k_mlp_tail(const float* __restrict__ zin,
                                                  const float* __restrict__ b1,
                                                  const float* __restrict__ W2,
                                                  const float* __restrict__ b2,
                                                  float* __restrict__ out) {
    __shared__ float sW2[64 * 64];
    __shared__ float sb1[64], sb2[64];
    for (int i = threadIdx.x; i < 64 * 64; i += 256) sW2[i] = W2[i];
    if (threadIdx.x < 64) { sb1[threadIdx.x] = b1[threadIdx.x]; sb2[threadIdx.x] = b2[threadIdx.x]; }
    __syncthreads();
    int node = blockIdx.x * 256 + threadIdx.x;
    const float* zr = zin + ((size_t)node << 6);
    float a[64];
#pragma unroll
    for (int c = 0; c < 64; c += 4) {
        float4 v = *(const float4*)(zr + c);
        a[c]     = fmaxf(v.x + sb1[c], 0.f);
        a[c + 1] = fmaxf(v.y + sb1[c + 1], 0.f);
        a[c + 2] = fmaxf(v.z + sb1[c + 2], 0.f);
        a[c + 3] = fmaxf(v.w + sb1[c + 3], 0.f);
    }
    second_matmul(a, sW2, sb2, out + ((size_t)node << 6));
}

// ---------------- layers 2-5 MLP: h = relu(relu(acc @ W1 + b1) @ W2 + b2)
__global__ __launch_bounds__(256) void k_mlp_dual(const float* __restrict__ zin,
                                                  const float* __restrict__ W1,
                                                  const float* __restrict__ b1,
                                                  const float* __restrict__ W2,
                                                  const float* __restrict__ b2,
                                                  float* __restrict__ out) {
    __shared__ float sW1[64 * 64];
    __shared__ float sW2[64 * 64];
    __shared__ float sb1[64], sb2[64];
    for (int i = threadIdx.x; i < 64 * 64; i += 256) { sW1[i] = W1[i]; sW2[i] = W2[i]; }
    if (threadIdx.x < 64) { sb1[threadIdx.x] = b1[threadIdx.x]; sb2[threadIdx.x] = b2[threadIdx.x]; }
    __syncthreads();
    int node = blockIdx.x * 256 + threadIdx.x;
    const float* zr = zin + ((size_t)node << 6);
    float a[64];
#pragma unroll
    for (int c = 0; c < 64; c++) a[c] = sb1[c];
    for (int k4 = 0; k4 < 16; k4++) {
        float4 xv = ((const float4*)zr)[k4];
        const float* w = sW1 + k4 * 256;
#pragma unroll
        for (int c = 0; c < 64; c++) a[c] += xv.x * w[c];
#pragma unroll
        for (int c = 0; c < 64; c++) a[c] += xv.y * w[64 + c];
#pragma unroll
        for (int c = 0; c < 64; c++) a[c] += xv.z * w[128 + c];
#pragma unroll
        for (int c = 0; c < 64; c++) a[c] += xv.w * w[192 + c];
    }
#pragma unroll
    for (int c = 0; c < 64; c++) a[c] = fmaxf(a[c], 0.f);
    second_matmul(a, sW2, sb2, out + ((size_t)node << 6));
}

// ---------------- BN stats: per-channel sum and sumsq into stats[0:64], stats[64:128]
__global__ __launch_bounds__(256) void k_bnstats(const float* __restrict__ h,
                                                 float* __restrict__ stats) {
    __shared__ float ss[128];
    if (threadIdx.x < 128) ss[threadIdx.x] = 0.f;
    __syncthreads();
    int tid = blockIdx.x * 256 + threadIdx.x;  // 65536 threads, stride keeps channel fixed
    int c4 = (tid & 15) * 4;
    float s0 = 0, s1 = 0, s2 = 0, s3 = 0, q0 = 0, q1 = 0, q2 = 0, q3 = 0;
    const float4* p = (const float4*)h;
    for (size_t i = tid; i < (size_t)NNODE * 16; i += 65536) {
        float4 v = p[i];
        s0 += v.x; q0 += v.x * v.x;
        s1 += v.y; q1 += v.y * v.y;
        s2 += v.z; q2 += v.z * v.z;
        s3 += v.w; q3 += v.w * v.w;
    }
    atomicAdd(&ss[c4], s0);      atomicAdd(&ss[c4 + 1], s1);
    atomicAdd(&ss[c4 + 2], s2);  atomicAdd(&ss[c4 + 3], s3);
    atomicAdd(&ss[64 + c4], q0); atomicAdd(&ss[64 + c4 + 1], q1);
    atomicAdd(&ss[64 + c4 + 2], q2); atomicAdd(&ss[64 + c4 + 3], q3);
    __syncthreads();
    if (threadIdx.x < 128) atomicAdd(&stats[threadIdx.x], ss[threadIdx.x]);
}

// ---------------- BN apply in place on h; optionally copy result into acc (next layer's base)
__global__ __launch_bounds__(256) void k_bnapply(float* __restrict__ h, float* __restrict__ acc,
                                                 const float* __restrict__ stats,
                                                 const float* __restrict__ gamma,
                                                 const float* __restrict__ beta, int do_copy) {
    size_t i = (size_t)blockIdx.x * 256 + threadIdx.x;
    int c0 = (int)(i & 15) * 4;
    const float invN = 1.0f / NNODE;
    float4 v = ((const float4*)h)[i];
    float sc[4], bi[4];
#pragma unroll
    for (int j = 0; j < 4; j++) {
        float mean = stats[c0 + j] * invN;
        float var = stats[64 + c0 + j] * invN - mean * mean;
        float s = gamma[c0 + j] * rsqrtf(var + BN_EPS);
        sc[j] = s;
        bi[j] = beta[c0 + j] - mean * s;
    }
    v.x = v.x * sc[0] + bi[0];
    v.y = v.y * sc[1] + bi[1];
    v.z = v.z * sc[2] + bi[2];
    v.w = v.w * sc[3] + bi[3];
    ((float4*)h)[i] = v;
    if (do_copy) ((float4*)acc)[i] = v;
}

// ---------------- pool + fc + relu + layernorm; one block per graph
__global__ __launch_bounds__(256) void k_final(const float* __restrict__ h,
                                               const float* __restrict__ fcw,
                                               const float* __restrict__ fcb,
                                               const float* __restrict__ lng,
                                               const float* __restrict__ lnb,
                                               float* __restrict__ y) {
    int b = blockIdx.x;
    int q = threadIdx.x >> 6;
    int c = threadIdx.x & 63;
    const float* base = h + (size_t)b * MAXLEN * 64;
    float s = 0.f;
    for (int p = q; p < MAXLEN; p += 4) s += base[p * 64 + c];
    __shared__ float sp[4][64];
    sp[q][c] = s;
    __syncthreads();
    __shared__ float pooled[64];
    if (threadIdx.x < 64) pooled[c] = sp[0][c] + sp[1][c] + sp[2][c] + sp[3][c];
    __syncthreads();
    if (threadIdx.x < 64) {
        float accv = fcb[c];
        for (int k = 0; k < 64; k++) accv += pooled[k] * fcw[k * 64 + c];
        accv = fmaxf(accv, 0.f);
        float t = accv;
        for (int o = 32; o; o >>= 1) t += __shfl_xor(t, o, 64);
        float mu = t * (1.0f / 64.0f);
        float d = accv - mu;
        float t2 = d * d;
        for (int o = 32; o; o >>= 1) t2 += __shfl_xor(t2, o, 64);
        float var = t2 * (1.0f / 64.0f);
        y[(size_t)b * 64 + c] = d * rsqrtf(var + LN_EPS) * lng[c] + lnb[c];
    }
}

extern "C" void kernel_launch(void* const* d_in, const int* in_sizes, int n_in,
                              void* d_out, int out_size, void* d_ws, size_t ws_size,
                              hipStream_t stream) {
    const float* x   = (const float*)d_in[0];
    const int*   ei  = (const int*)d_in[1];
    // d_in[2]=batch, d_in[3]=batch_len, d_in[4]=max_len : structure is fixed, unused
    const float* w1a = (const float*)d_in[5];
    const float* b1a = (const float*)d_in[6];
    const float* w1b = (const float*)d_in[7];
    const float* b1b = (const float*)d_in[8];
    const float* Wa  = (const float*)d_in[9];
    const float* ba  = (const float*)d_in[10];
    const float* Wb  = (const float*)d_in[11];
    const float* bb  = (const float*)d_in[12];
    const float* bng = (const float*)d_in[13];
    const float* bnb = (const float*)d_in[14];
    const float* fcw = (const float*)d_in[15];
    const float* fcb = (const float*)d_in[16];
    const float* lng = (const float*)d_in[17];
    const float* lnb = (const float*)d_in[18];

    float* h   = (float*)d_out;                   // N*64 region == x_seq (identity layout)
    float* y   = h + (size_t)NNODE * 64;          // B*64 region
    float* acc = (float*)d_ws;                    // N*64 accumulator (h + agg)
    float* stats = acc + (size_t)NNODE * 64;      // 5 * 128 floats of BN sums

    const int NB_NODE = NNODE / 256;              // 2032
    const int NB_VEC  = NNODE * 16 / 256;         // 32512 (N*64 as float4)
    const int NB_EDGE = (NEDGE / 16) * 256 / 256; // threads = NEDGE*16
    (void)in_sizes; (void)n_in; (void)out_size; (void)ws_size;

    // ---- layer 1 (transform-first: t = x@w1a, then aggregate in 64-dim space)
    k_gemm78<<<NB_NODE, 256, 0, stream>>>(x, w1a, h, stats);
    k_copy<<<NB_VEC, 256, 0, stream>>>((const float4*)h, (float4*)acc);
    k_edge<<<(NEDGE * 16) / 256, 256, 0, stream>>>(h, ei, acc);
    k_mlp_tail<<<NB_NODE, 256, 0, stream>>>(acc, b1a, w1b, b1b, h);
    k_bnstats<<<256, 256, 0, stream>>>(h, stats);
    k_bnapply<<<NB_VEC, 256, 0, stream>>>(h, acc, stats, bng, bnb, 1);

    // ---- layers 2..5
    for (int L = 1; L <= 4; L++) {
        k_edge<<<(NEDGE * 16) / 256, 256, 0, stream>>>(h, ei, acc);
        k_mlp_dual<<<NB_NODE, 256, 0, stream>>>(acc, Wa + (size_t)(L - 1) * 4096,
                                                ba + (size_t)(L - 1) * 64,
                                                Wb + (size_t)(L - 1) * 4096,
                                                bb + (size_t)(L - 1) * 64, h);
        k_bnstats<<<256, 256, 0, stream>>>(h, stats + L * 128);
        k_bnapply<<<NB_VEC, 256, 0, stream>>>(h, (L < 4) ? acc : h, stats + L * 128,
                                              bng + L * 64, bnb + L * 64, (L < 4) ? 1 : 0);
    }

    // ---- pooled -> fc -> relu -> layernorm
    k_final<<<NGRAPH, 256, 0, stream>>>(h, fcw, fcb, lng, lnb, y);
    (void)NB_EDGE;
}

// Round 2
// 3086.617 us; speedup vs baseline: 6.2724x; 6.2724x over previous
//
#include <hip/hip_runtime.h>

#define NGRAPH 2048
#define MAXLEN 254
#define NNODE 520192      // NGRAPH * MAXLEN
#define NEDGE 4161536     // NNODE * 8
#define NF 78
#define BN_EPS 1e-5f
#define LN_EPS 1e-5f

// ---------------- init: zero degree array, BN stats, total counter
__global__ __launch_bounds__(256) void k_init(int* __restrict__ deg, float* __restrict__ stats,
                                              int* __restrict__ total) {
    int i = blockIdx.x * 256 + threadIdx.x;
    deg[i] = 0;
    if (blockIdx.x == 0) {
        for (int j = threadIdx.x; j < 5 * 128; j += 256) stats[j] = 0.f;
        if (threadIdx.x == 0) *total = 0;
    }
}

// ---------------- in-degree histogram
__global__ __launch_bounds__(256) void k_hist(const int* __restrict__ ei, int* __restrict__ deg) {
    int e = blockIdx.x * 256 + threadIdx.x;  // NEDGE threads exactly
    atomicAdd(&deg[ei[NEDGE + e]], 1);
}

// ---------------- row offsets: wave-level exclusive scan + one atomic per wave
__global__ __launch_bounds__(256) void k_scan(const int* __restrict__ deg,
                                              int* __restrict__ row_start,
                                              int* __restrict__ cursor, int* __restrict__ total) {
    int i = blockIdx.x * 256 + threadIdx.x;
    int d = deg[i];
    int lane = threadIdx.x & 63;
    int v = d;
#pragma unroll
    for (int o = 1; o < 64; o <<= 1) {
        int t = __shfl_up(v, o, 64);
        if (lane >= o) v += t;
    }
    int wsum = __shfl(v, 63, 64);
    int base = 0;
    if (lane == 63) base = atomicAdd(total, wsum);
    base = __shfl(base, 63, 64);
    int start = base + v - d;
    row_start[i] = start;
    cursor[i] = start;
}

// ---------------- scatter src ids into per-dst contiguous lists
__global__ __launch_bounds__(256) void k_fill(const int* __restrict__ ei, int* __restrict__ cursor,
                                              int* __restrict__ elist) {
    int e = blockIdx.x * 256 + threadIdx.x;
    int d = ei[NEDGE + e];
    int p = atomicAdd(&cursor[d], 1);
    elist[p] = ei[e];
}

// ---------------- CSR gather: acc[i] = h[i] + sum_{j->i} h[j]; 16 lanes per node
__global__ __launch_bounds__(256) void k_gather(const float* __restrict__ h,
                                                const int* __restrict__ elist,
                                                const int* __restrict__ row_start,
                                                const int* __restrict__ deg,
                                                float* __restrict__ acc) {
    size_t t = (size_t)blockIdx.x * 256 + threadIdx.x;  // NNODE*16 threads
    int node = (int)(t >> 4);
    int g = (int)(t & 15) * 4;
    int rs = row_start[node];
    int dg = deg[node];
    float4 a = *(const float4*)(h + ((size_t)node << 6) + g);
    for (int e = 0; e < dg; e++) {
        int s = elist[rs + e];
        float4 v = *(const float4*)(h + ((size_t)s << 6) + g);
        a.x += v.x; a.y += v.y; a.z += v.z; a.w += v.w;
    }
    *(float4*)(acc + ((size_t)node << 6) + g) = a;
}

// ---------------- layer-1 first GEMM: t = x @ w1a (N x 78 @ 78 x 64)
__global__ __launch_bounds__(256) void k_gemm78(const float* __restrict__ x,
                                                const float* __restrict__ W,
                                                float* __restrict__ out) {
    __shared__ float sW[NF * 64];
    for (int i = threadIdx.x; i < NF * 64; i += 256) sW[i] = W[i];
    __syncthreads();
    int node = blockIdx.x * 256 + threadIdx.x;  // N divisible by 256
    const float* xr = x + (size_t)node * NF;    // rows are 8B-aligned (312B) -> float2
    float a[64];
#pragma unroll
    for (int c = 0; c < 64; c++) a[c] = 0.f;
    for (int k2 = 0; k2 < NF / 2; k2++) {
        float2 xv = ((const float2*)xr)[k2];
        const float* w0 = sW + (2 * k2) * 64;
#pragma unroll
        for (int c = 0; c < 64; c++) a[c] += xv.x * w0[c];
#pragma unroll
        for (int c = 0; c < 64; c++) a[c] += xv.y * w0[64 + c];
    }
    float* orow = out + ((size_t)node << 6);
#pragma unroll
    for (int c = 0; c < 64; c += 4)
        *(float4*)(orow + c) = make_float4(a[c], a[c + 1], a[c + 2], a[c + 3]);
}

// ---------------- shared second matmul: out = relu(a @ W2 + b2)
__device__ __forceinline__ void second_matmul(const float (&a)[64], const float* __restrict__ sW2,
                                              const float* __restrict__ sb2,
                                              float* __restrict__ orow) {
#pragma unroll
    for (int cb = 0; cb < 64; cb += 16) {
        float o[16];
#pragma unroll
        for (int j = 0; j < 16; j++) o[j] = sb2[cb + j];
#pragma unroll
        for (int k = 0; k < 64; k++) {
            float ak = a[k];
#pragma unroll
            for (int j = 0; j < 16; j++) o[j] += ak * sW2[k * 64 + cb + j];
        }
#pragma unroll
        for (int j = 0; j < 16; j += 4)
            *(float4*)(orow + cb + j) =
                make_float4(fmaxf(o[j], 0.f), fmaxf(o[j + 1], 0.f),
                            fmaxf(o[j + 2], 0.f), fmaxf(o[j + 3], 0.f));
    }
}

// ---------------- layer-1 tail: h = relu(relu(acc + b1a) @ w1b + b1b)
__global__ __launch_bounds__(256) void k_mlp_tail(const float* __restrict__ zin,
                                                  const float* __restrict__ b1,
                                                  const float* __restrict__ W2,
                                                  const float* __restrict__ b2,
                                                  float* __restrict__ out) {
    __shared__ float sW2[64 * 64];
    __shared__ float sb1[64], sb2[64];
    for (int i = threadIdx.x; i < 64 * 64; i += 256) sW2[i] = W2[i];
    if (threadIdx.x < 64) { sb1[threadIdx.x] = b1[threadIdx.x]; sb2[threadIdx.x] = b2[threadIdx.x]; }
    __syncthreads();
    int node = blockIdx.x * 256 + threadIdx.x;
    const float* zr = zin + ((size_t)node << 6);
    float a[64];
#pragma unroll
    for (int c = 0; c < 64; c += 4) {
        float4 v = *(const float4*)(zr + c);
        a[c]     = fmaxf(v.x + sb1[c], 0.f);
        a[c + 1] = fmaxf(v.y + sb1[c + 1], 0.f);
        a[c + 2] = fmaxf(v.z + sb1[c + 2], 0.f);
        a[c + 3] = fmaxf(v.w + sb1[c + 3], 0.f);
    }
    second_matmul(a, sW2, sb2, out + ((size_t)node << 6));
}

// ---------------- layers 2-5 MLP: h = relu(relu(acc @ W1 + b1) @ W2 + b2)
__global__ __launch_bounds__(256) void k_mlp_dual(const float* __restrict__ zin,
                                                  const float* __restrict__ W1,
                                                  const float* __restrict__ b1,
                                                  const float* __restrict__ W2,
                                                  const float* __restrict__ b2,
                                                  float* __restrict__ out) {
    __shared__ float sW1[64 * 64];
    __shared__ float sW2[64 * 64];
    __shared__ float sb1[64], sb2[64];
    for (int i = threadIdx.x; i < 64 * 64; i += 256) { sW1[i] = W1[i]; sW2[i] = W2[i]; }
    if (threadIdx.x < 64) { sb1[threadIdx.x] = b1[threadIdx.x]; sb2[threadIdx.x] = b2[threadIdx.x]; }
    __syncthreads();
    int node = blockIdx.x * 256 + threadIdx.x;
    const float* zr = zin + ((size_t)node << 6);
    float a[64];
#pragma unroll
    for (int c = 0; c < 64; c++) a[c] = sb1[c];
    for (int k4 = 0; k4 < 16; k4++) {
        float4 xv = ((const float4*)zr)[k4];
        const float* w = sW1 + k4 * 256;
#pragma unroll
        for (int c = 0; c < 64; c++) a[c] += xv.x * w[c];
#pragma unroll
        for (int c = 0; c < 64; c++) a[c] += xv.y * w[64 + c];
#pragma unroll
        for (int c = 0; c < 64; c++) a[c] += xv.z * w[128 + c];
#pragma unroll
        for (int c = 0; c < 64; c++) a[c] += xv.w * w[192 + c];
    }
#pragma unroll
    for (int c = 0; c < 64; c++) a[c] = fmaxf(a[c], 0.f);
    second_matmul(a, sW2, sb2, out + ((size_t)node << 6));
}

// ---------------- BN stats: per-channel sum and sumsq into stats[0:64], stats[64:128]
__global__ __launch_bounds__(256) void k_bnstats(const float* __restrict__ h,
                                                 float* __restrict__ stats) {
    __shared__ float ss[128];
    if (threadIdx.x < 128) ss[threadIdx.x] = 0.f;
    __syncthreads();
    int tid = blockIdx.x * 256 + threadIdx.x;  // 65536 threads, stride keeps channel fixed
    int c4 = (tid & 15) * 4;
    float s0 = 0, s1 = 0, s2 = 0, s3 = 0, q0 = 0, q1 = 0, q2 = 0, q3 = 0;
    const float4* p = (const float4*)h;
    for (size_t i = tid; i < (size_t)NNODE * 16; i += 65536) {
        float4 v = p[i];
        s0 += v.x; q0 += v.x * v.x;
        s1 += v.y; q1 += v.y * v.y;
        s2 += v.z; q2 += v.z * v.z;
        s3 += v.w; q3 += v.w * v.w;
    }
    atomicAdd(&ss[c4], s0);      atomicAdd(&ss[c4 + 1], s1);
    atomicAdd(&ss[c4 + 2], s2);  atomicAdd(&ss[c4 + 3], s3);
    atomicAdd(&ss[64 + c4], q0); atomicAdd(&ss[64 + c4 + 1], q1);
    atomicAdd(&ss[64 + c4 + 2], q2); atomicAdd(&ss[64 + c4 + 3], q3);
    __syncthreads();
    if (threadIdx.x < 128) atomicAdd(&stats[threadIdx.x], ss[threadIdx.x]);
}

// ---------------- BN apply in place on h
__global__ __launch_bounds__(256) void k_bnapply(float* __restrict__ h,
                                                 const float* __restrict__ stats,
                                                 const float* __restrict__ gamma,
                                                 const float* __restrict__ beta) {
    size_t i = (size_t)blockIdx.x * 256 + threadIdx.x;
    int c0 = (int)(i & 15) * 4;
    const float invN = 1.0f / NNODE;
    float4 v = ((const float4*)h)[i];
    float sc[4], bi[4];
#pragma unroll
    for (int j = 0; j < 4; j++) {
        float mean = stats[c0 + j] * invN;
        float var = stats[64 + c0 + j] * invN - mean * mean;
        float s = gamma[c0 + j] * rsqrtf(var + BN_EPS);
        sc[j] = s;
        bi[j] = beta[c0 + j] - mean * s;
    }
    v.x = v.x * sc[0] + bi[0];
    v.y = v.y * sc[1] + bi[1];
    v.z = v.z * sc[2] + bi[2];
    v.w = v.w * sc[3] + bi[3];
    ((float4*)h)[i] = v;
}

// ---------------- pool + fc + relu + layernorm; one block per graph
__global__ __launch_bounds__(256) void k_final(const float* __restrict__ h,
                                               const float* __restrict__ fcw,
                                               const float* __restrict__ fcb,
                                               const float* __restrict__ lng,
                                               const float* __restrict__ lnb,
                                               float* __restrict__ y) {
    int b = blockIdx.x;
    int q = threadIdx.x >> 6;
    int c = threadIdx.x & 63;
    const float* base = h + (size_t)b * MAXLEN * 64;
    float s = 0.f;
    for (int p = q; p < MAXLEN; p += 4) s += base[p * 64 + c];
    __shared__ float sp[4][64];
    sp[q][c] = s;
    __syncthreads();
    __shared__ float pooled[64];
    if (threadIdx.x < 64) pooled[c] = sp[0][c] + sp[1][c] + sp[2][c] + sp[3][c];
    __syncthreads();
    if (threadIdx.x < 64) {
        float accv = fcb[c];
        for (int k = 0; k < 64; k++) accv += pooled[k] * fcw[k * 64 + c];
        accv = fmaxf(accv, 0.f);
        float t = accv;
        for (int o = 32; o; o >>= 1) t += __shfl_xor(t, o, 64);
        float mu = t * (1.0f / 64.0f);
        float d = accv - mu;
        float t2 = d * d;
        for (int o = 32; o; o >>= 1) t2 += __shfl_xor(t2, o, 64);
        float var = t2 * (1.0f / 64.0f);
        y[(size_t)b * 64 + c] = d * rsqrtf(var + LN_EPS) * lng[c] + lnb[c];
    }
}

extern "C" void kernel_launch(void* const* d_in, const int* in_sizes, int n_in,
                              void* d_out, int out_size, void* d_ws, size_t ws_size,
                              hipStream_t stream) {
    const float* x   = (const float*)d_in[0];
    const int*   ei  = (const int*)d_in[1];
    // d_in[2]=batch, d_in[3]=batch_len, d_in[4]=max_len : structure is fixed, unused
    const float* w1a = (const float*)d_in[5];
    const float* b1a = (const float*)d_in[6];
    const float* w1b = (const float*)d_in[7];
    const float* b1b = (const float*)d_in[8];
    const float* Wa  = (const float*)d_in[9];
    const float* ba  = (const float*)d_in[10];
    const float* Wb  = (const float*)d_in[11];
    const float* bb  = (const float*)d_in[12];
    const float* bng = (const float*)d_in[13];
    const float* bnb = (const float*)d_in[14];
    const float* fcw = (const float*)d_in[15];
    const float* fcb = (const float*)d_in[16];
    const float* lng = (const float*)d_in[17];
    const float* lnb = (const float*)d_in[18];

    float* h   = (float*)d_out;                   // N*64 region == x_seq (identity layout)
    float* y   = h + (size_t)NNODE * 64;          // B*64 region
    float* acc = (float*)d_ws;                    // N*64 accumulator (h + agg)
    float* stats = acc + (size_t)NNODE * 64;      // 5 * 128 floats of BN sums
    int* deg       = (int*)(stats + 5 * 128);
    int* row_start = deg + NNODE;
    int* cursor    = row_start + NNODE;
    int* total     = cursor + NNODE;
    int* elist     = total + 4;                   // NEDGE src ids grouped by dst

    const int NB_NODE = NNODE / 256;              // 2032
    const int NB_VEC  = NNODE * 16 / 256;         // 32512 (N*64 as float4)
    const int NB_EDGE = NEDGE / 256;              // 16256
    (void)in_sizes; (void)n_in; (void)out_size; (void)ws_size;

    // ---- build CSR (by dst) once per call; edges reused by all 5 layers
    k_init<<<NB_NODE, 256, 0, stream>>>(deg, stats, total);
    k_hist<<<NB_EDGE, 256, 0, stream>>>(ei, deg);
    k_scan<<<NB_NODE, 256, 0, stream>>>(deg, row_start, cursor, total);
    k_fill<<<NB_EDGE, 256, 0, stream>>>(ei, cursor, elist);

    // ---- layer 1 (transform-first: t = x@w1a, then aggregate in 64-dim space)
    k_gemm78<<<NB_NODE, 256, 0, stream>>>(x, w1a, h);
    k_gather<<<NB_VEC, 256, 0, stream>>>(h, elist, row_start, deg, acc);
    k_mlp_tail<<<NB_NODE, 256, 0, stream>>>(acc, b1a, w1b, b1b, h);
    k_bnstats<<<256, 256, 0, stream>>>(h, stats);
    k_bnapply<<<NB_VEC, 256, 0, stream>>>(h, stats, bng, bnb);

    // ---- layers 2..5
    for (int L = 1; L <= 4; L++) {
        k_gather<<<NB_VEC, 256, 0, stream>>>(h, elist, row_start, deg, acc);
        k_mlp_dual<<<NB_NODE, 256, 0, stream>>>(acc, Wa + (size_t)(L - 1) * 4096,
                                                ba + (size_t)(L - 1) * 64,
                                                Wb + (size_t)(L - 1) * 4096,
                                                bb + (size_t)(L - 1) * 64, h);
        k_bnstats<<<256, 256, 0, stream>>>(h, stats + L * 128);
        k_bnapply<<<NB_VEC, 256, 0, stream>>>(h, stats + L * 128, bng + L * 64, bnb + L * 64);
    }

    // ---- pooled -> fc -> relu -> layernorm
    k_final<<<NGRAPH, 256, 0, stream>>>(h, fcw, fcb, lng, lnb, y);
}